// Round 15
// baseline (6871.824 us; speedup 1.0000x reference)
//
#include <hip/hip_runtime.h>
#include <math.h>

#define NLAB 28000
#define NEDGE 224000
#define XFS 224

typedef _Float16 f16;
typedef _Float16 f16x8 __attribute__((ext_vector_type(8)));
typedef float f32x4 __attribute__((ext_vector_type(4)));

// ---------------------------------------------------------------- utils

__device__ __forceinline__ void atomAddF(float* p, float v) {
  unsafeAtomicAdd(p, v);
}

struct RecurArgs {
  const float* gx[4];
  const float* wF[4];   // packed f16 frags: hi[40*7*512] then lo[40*7*512]
  const float* bh[4];
  float* out[4];
  const int* len[4];
  int Tl[4];
  int dir[4];
};

#define COMPB(V, B) ((B) == 0 ? (V).x : (B) == 1 ? (V).y : (B) == 2 ? (V).z : (V).w)

// ---------------------------------------------------------------- embed

__global__ void embed_gather(const int* __restrict__ tok, const float* __restrict__ emb,
                             float* __restrict__ x, int rows) {
  int idx = blockIdx.x * blockDim.x + threadIdx.x;
  if (idx >= rows * 50) return;
  int r = idx / 50, c = idx - r * 50;
  *(float4*)&x[(size_t)r * 200 + c * 4] =
      *(const float4*)&emb[(size_t)tok[r] * 200 + c * 4];
}

// ---------------------------------------------------------------- whh -> MFMA A-frag pack (f16 hi/lo)

__global__ void pack_whhF(const float* __restrict__ whh, f16* __restrict__ out) {
  int e = blockIdx.x * 256 + threadIdx.x;
  if (e >= 40 * 7 * 512) return;
  int frag = e >> 9, r = e & 511;
  int l = r >> 3, j = r & 7;
  int mt = frag / 7, kt = frag - mt * 7;
  int m = mt * 16 + (l & 15);
  int k = kt * 32 + ((l >> 4) << 2) + (j & 3) + ((j >> 2) << 4);
  float v = (m < 600 && k < 200) ? whh[(size_t)m * 200 + k] : 0.f;
  f16 hi = (f16)v;
  out[e] = hi;
  out[40 * 7 * 512 + e] = (f16)((v - (float)hi) * 2048.f);
}

// ---------------------------------------------------------------- generic C[M,N] = A[M,K] * W[N,K]^T (+bias)(+relu)

template <int RELU, int BIAS>
__global__ __launch_bounds__(256, 2) void gemm_nt(
    const float* __restrict__ A, const float* __restrict__ Wt,
    const float* __restrict__ bias, float* __restrict__ C,
    int M, int N, int K, int ldc) {
  __shared__ float As[16][68];
  __shared__ float Bs[16][68];
  int tx = threadIdx.x & 15, ty = threadIdx.x >> 4;
  int m0 = blockIdx.y * 64, n0 = blockIdx.x * 64;
  float c[4][4] = {};
  int row = threadIdx.x >> 2;
  int kk = (threadIdx.x & 3) * 4;
  for (int k0 = 0; k0 < K; k0 += 16) {
    int gk = k0 + kk;
    float a0 = 0, a1 = 0, a2 = 0, a3 = 0;
    float b0 = 0, b1 = 0, b2 = 0, b3 = 0;
    int gm = m0 + row;
    if (gm < M) {
      if (gk + 3 < K) {
        float4 v = *(const float4*)&A[(size_t)gm * K + gk];
        a0 = v.x; a1 = v.y; a2 = v.z; a3 = v.w;
      } else {
        if (gk + 0 < K) a0 = A[(size_t)gm * K + gk + 0];
        if (gk + 1 < K) a1 = A[(size_t)gm * K + gk + 1];
        if (gk + 2 < K) a2 = A[(size_t)gm * K + gk + 2];
        if (gk + 3 < K) a3 = A[(size_t)gm * K + gk + 3];
      }
    }
    int gn = n0 + row;
    if (gn < N) {
      if (gk + 3 < K) {
        float4 v = *(const float4*)&Wt[(size_t)gn * K + gk];
        b0 = v.x; b1 = v.y; b2 = v.z; b3 = v.w;
      } else {
        if (gk + 0 < K) b0 = Wt[(size_t)gn * K + gk + 0];
        if (gk + 1 < K) b1 = Wt[(size_t)gn * K + gk + 1];
        if (gk + 2 < K) b2 = Wt[(size_t)gn * K + gk + 2];
        if (gk + 3 < K) b3 = Wt[(size_t)gn * K + gk + 3];
      }
    }
    As[kk + 0][row] = a0; As[kk + 1][row] = a1; As[kk + 2][row] = a2; As[kk + 3][row] = a3;
    Bs[kk + 0][row] = b0; Bs[kk + 1][row] = b1; Bs[kk + 2][row] = b2; Bs[kk + 3][row] = b3;
    __syncthreads();
#pragma unroll
    for (int k = 0; k < 16; k++) {
      float4 a4 = *(const float4*)&As[k][ty * 4];
      float4 b4 = *(const float4*)&Bs[k][tx * 4];
      c[0][0] = fmaf(a4.x, b4.x, c[0][0]); c[0][1] = fmaf(a4.x, b4.y, c[0][1]);
      c[0][2] = fmaf(a4.x, b4.z, c[0][2]); c[0][3] = fmaf(a4.x, b4.w, c[0][3]);
      c[1][0] = fmaf(a4.y, b4.x, c[1][0]); c[1][1] = fmaf(a4.y, b4.y, c[1][1]);
      c[1][2] = fmaf(a4.y, b4.z, c[1][2]); c[1][3] = fmaf(a4.y, b4.w, c[1][3]);
      c[2][0] = fmaf(a4.z, b4.x, c[2][0]); c[2][1] = fmaf(a4.z, b4.y, c[2][1]);
      c[2][2] = fmaf(a4.z, b4.z, c[2][2]); c[2][3] = fmaf(a4.z, b4.w, c[2][3]);
      c[3][0] = fmaf(a4.w, b4.x, c[3][0]); c[3][1] = fmaf(a4.w, b4.y, c[3][1]);
      c[3][2] = fmaf(a4.w, b4.z, c[3][2]); c[3][3] = fmaf(a4.w, b4.w, c[3][3]);
    }
    __syncthreads();
  }
#pragma unroll
  for (int i = 0; i < 4; i++) {
    int gm = m0 + ty * 4 + i;
    if (gm >= M) continue;
#pragma unroll
    for (int j = 0; j < 4; j++) {
      int gn = n0 + tx * 4 + j;
      if (gn >= N) continue;
      float v = c[i][j];
      if (BIAS) v += bias[gn];
      if (RELU) v = fmaxf(v, 0.f);
      C[(size_t)gm * ldc + gn] = v;
    }
  }
}

// ---------------------------------------------------------------- GRU + GCN fused dispatch
// Blocks 0-3: GRU chain (round-10 structure: 16 hi tiles in LDS, h/bhs in LDS).
// Blocks 4..67: edge scatter-add (64 blocks, throttled to cut L2 interference
// with the GRU's weight stream), arrive barrier, inline GCN linear; dispatch B
// adds cvt_lf after a second barrier. All hidden under the 2.3ms recurrence.

__global__ __launch_bounds__(512, 1) void gru_fused(RecurArgs a,
    const float* __restrict__ gfeat, const int* __restrict__ esrc,
    const int* __restrict__ edst, float* __restrict__ gagg,
    const float* __restrict__ gw, const float* __restrict__ gb,
    float* __restrict__ gout, int relu, int doCvt,
    const float* __restrict__ gnfp, f16* __restrict__ lfFp, int* __restrict__ cnt) {
  __shared__ __align__(16) f16 wlds[16][7][512];   // 112 KB hi tiles (gather blocks: arow alias)
  __shared__ __align__(16) f16 hfrag[2][7][512];   // [hi|lo][kt][frag]
  __shared__ float h[200][4];
  __shared__ float gh[600][4];
  __shared__ float bhs[600];
  __shared__ int lens[4];

  if (blockIdx.x >= 4) {
    int tid = threadIdx.x;
    int lane = tid & 63;
    int nb = gridDim.x - 4;
    // ---- GCN edge gather ----
    if (lane < 50) {
      int wav = (blockIdx.x - 4) * 8 + (tid >> 6);
      for (int e = wav; e < NEDGE; e += nb * 8) {
        int s = esrc[e], d = edst[e];
        float4 v = *(const float4*)&gfeat[(size_t)s * 200 + lane * 4];
        float* p = &gagg[(size_t)d * 200 + lane * 4];
        atomAddF(p + 0, v.x); atomAddF(p + 1, v.y);
        atomAddF(p + 2, v.z); atomAddF(p + 3, v.w);
      }
    }
    // ---- barrier 0: all gather atomics done ----
    __syncthreads();
    if (tid == 0) {
      __threadfence();
      __hip_atomic_fetch_add(&cnt[0], 1, __ATOMIC_ACQ_REL, __HIP_MEMORY_SCOPE_AGENT);
      while (__hip_atomic_load(&cnt[0], __ATOMIC_ACQUIRE, __HIP_MEMORY_SCOPE_AGENT) < nb) {}
    }
    __syncthreads();
    // ---- GCN linear ----
    float* arow = (float*)wlds;
    for (int m = blockIdx.x - 4; m < NLAB; m += nb) {
      __syncthreads();
      for (int k = tid; k < 200; k += 512) arow[k] = gagg[(size_t)m * 200 + k];
      __syncthreads();
      if (tid < 200) {
        float acc = gb[tid];
        const float* wr = gw + (size_t)tid * 200;
#pragma unroll 4
        for (int k = 0; k < 200; k++) acc = fmaf(arow[k], wr[k], acc);
        if (relu) acc = fmaxf(acc, 0.f);
        gout[(size_t)m * 200 + tid] = acc;
      }
    }
    if (doCvt) {
      __syncthreads();
      if (tid == 0) {
        __threadfence();
        __hip_atomic_fetch_add(&cnt[1], 1, __ATOMIC_ACQ_REL, __HIP_MEMORY_SCOPE_AGENT);
        while (__hip_atomic_load(&cnt[1], __ATOMIC_ACQUIRE, __HIP_MEMORY_SCOPE_AGENT) < nb) {}
      }
      __syncthreads();
      for (int e = (blockIdx.x - 4) * 512 + tid; e < 1752 * 13 * 512; e += nb * 512) {
        int frag = e >> 9, r = e & 511;
        int l = r >> 3, j = r & 7;
        int nsub = frag / 13, kt = frag - nsub * 13;
        int label = nsub * 16 + (l & 15);
        int k = kt * 32 + ((l >> 4) << 2) + (j & 3) + ((j >> 2) << 4);
        float v = 0.f;
        if (label < NLAB && k < 400)
          v = (k < 200) ? gout[(size_t)label * 200 + k] : gnfp[(size_t)label * 200 + k - 200];
        lfFp[e] = (f16)v;
      }
    }
    return;
  }

  int blk = blockIdx.x;
  const float* __restrict__ gx = a.gx[blk];
  const f16* __restrict__ whiP = (const f16*)a.wF[blk];
  const float* __restrict__ bh = a.bh[blk];
  float* __restrict__ outp = a.out[blk];
  const int* lenp = a.len[blk];
  int TT = a.Tl[blk];
  int bwd = a.dir[blk];
  int dirOff = bwd ? 200 : 0;

  int tid = threadIdx.x, lane = tid & 63, w = tid >> 6;
  int l15 = lane & 15, lg = lane >> 4;

  for (int i = tid; i < 800; i += 512) ((float*)h)[i] = 0.f;
  for (int i = tid; i < 600; i += 512) bhs[i] = bh[i];
  for (int i = tid; i < 2 * 7 * 512; i += 512) ((f16*)hfrag)[i] = (f16)0.f;
  if (tid < 4) lens[tid] = lenp[tid];

  // one-time fill of LDS-resident hi tiles (wave w: M-tiles 5w, 5w+1)
#pragma unroll
  for (int i = 0; i < 2; i++)
#pragma unroll
    for (int kt = 0; kt < 7; kt++)
      *(f16x8*)&wlds[w * 2 + i][kt][lane * 8] =
          *(const f16x8*)(whiP + ((size_t)((w * 5 + i) * 7 + kt)) * 512 + lane * 8);
  __syncthreads();
  int maxlen = max(max(lens[0], lens[1]), max(lens[2], lens[3]));

  for (int s = 0; s < maxlen; s++) {
    // ---- gx prefetch: retire under phase A's weight stream
    float pgx[3][4];
    if (tid < 200) {
#pragma unroll
      for (int b = 0; b < 4; b++) {
        int Lb = lens[b];
        if (s < Lb) {
          int ta = bwd ? (Lb - 1 - s) : s;
          const float* gxr = gx + (size_t)(b * TT + ta) * 600;
          pgx[0][b] = gxr[tid];
          pgx[1][b] = gxr[200 + tid];
          pgx[2][b] = gxr[400 + tid];
        }
      }
    }
    // ---- phase A: MFMA matvec (hi: 2 tiles LDS + 3 streamed; lo: 5 streamed)
    f32x4 acc1[5], acc2[5];
#pragma unroll
    for (int i = 0; i < 5; i++) {
      acc1[i] = (f32x4){0.f, 0.f, 0.f, 0.f};
      acc2[i] = (f32x4){0.f, 0.f, 0.f, 0.f};
    }
#pragma unroll
    for (int kt = 0; kt < 7; kt++) {
      f16x8 hhi = *(const f16x8*)&hfrag[0][kt][lane * 8];
      f16x8 hlo = *(const f16x8*)&hfrag[1][kt][lane * 8];
#pragma unroll
      for (int i = 0; i < 5; i++) {
        const f16* base = whiP + ((size_t)((w * 5 + i) * 7 + kt)) * 512 + lane * 8;
        f16x8 whi = (i < 2) ? *(const f16x8*)&wlds[w * 2 + i][kt][lane * 8]
                            : *(const f16x8*)base;
        f16x8 wlo = *(const f16x8*)(base + (size_t)40 * 7 * 512);
        acc1[i] = __builtin_amdgcn_mfma_f32_16x16x32_f16(whi, hhi, acc1[i], 0, 0, 0);
        acc2[i] = __builtin_amdgcn_mfma_f32_16x16x32_f16(wlo, hhi, acc2[i], 0, 0, 0);
        acc2[i] = __builtin_amdgcn_mfma_f32_16x16x32_f16(whi, hlo, acc2[i], 0, 0, 0);
      }
    }
    if (l15 < 4) {
#pragma unroll
      for (int i = 0; i < 5; i++) {
        int mbase = (w * 5 + i) * 16 + lg * 4;
#pragma unroll
        for (int r = 0; r < 4; r++) {
          int m = mbase + r;
          if (m < 600) gh[m][l15] = acc1[i][r] + acc2[i][r] * (1.f / 2048.f);
        }
      }
    }
    __syncthreads();
    // ---- phase B: gates + h update + output + h-frag write
    if (tid < 200) {
      int u = tid;
      float4 hold = *(const float4*)&h[u][0];
      float4 hnew = hold;
      float br = bhs[u], bz = bhs[200 + u], bn = bhs[400 + u];
#pragma unroll
      for (int b = 0; b < 4; b++) {
        int Lb = lens[b];
        if (s < Lb) {
          int ta = bwd ? (Lb - 1 - s) : s;
          float r = 1.f / (1.f + expf(-(pgx[0][b] + gh[u][b] + br)));
          float z = 1.f / (1.f + expf(-(pgx[1][b] + gh[200 + u][b] + bz)));
          float n = tanhf(pgx[2][b] + r * (gh[400 + u][b] + bn));
          float hn = (1.f - z) * n + z * COMPB(hold, b);
          if (b == 0) hnew.x = hn; else if (b == 1) hnew.y = hn;
          else if (b == 2) hnew.z = hn; else hnew.w = hn;
          outp[(size_t)(b * TT + ta) * 400 + dirOff + u] = hn;
        }
      }
      *(float4*)&h[u][0] = hnew;
      int kt = u >> 5;
      int lbase = ((u >> 2) & 3) << 4;
      int j = (u & 3) | (((u >> 4) & 1) << 2);
#pragma unroll
      for (int b = 0; b < 4; b++) {
        float hv = COMPB(hnew, b);
        f16 hi = (f16)hv;
        f16 lo = (f16)((hv - (float)hi) * 2048.f);
        hfrag[0][kt][(lbase + b) * 8 + j] = hi;
        hfrag[1][kt][(lbase + b) * 8 + j] = lo;
      }
    }
    __syncthreads();
  }
}

// ---------------------------------------------------------------- f16 fragment prep kernels

__global__ void cvt_x_frags(const float* __restrict__ x, f16* __restrict__ out, int TT) {
  int e = blockIdx.x * 256 + threadIdx.x;
  if (e >= 4 * TT * 13 * 512) return;
  int frag = e >> 9, r = e & 511;
  int l = r >> 3, j = r & 7;
  int kt = frag % 13, bt = frag / 13;
  int tt = bt % TT, b = bt / TT;
  int t = tt * 16 + (l & 15);
  int k = kt * 32 + ((l >> 4) << 2) + (j & 3) + ((j >> 2) << 4);
  float v = (k < 400) ? x[((size_t)b * TT * 16 + t) * 400 + k] : 0.f;
  out[e] = (f16)v;
}

__global__ void cvt_v_frags(const float* __restrict__ xf, f16* __restrict__ out, int KT) {
  int e = blockIdx.x * 256 + threadIdx.x;
  if (e >= 4 * KT * 13 * 2 * 512) return;
  int idx = e >> 9, r = e & 511;
  int l = r >> 3, j = r & 7;
  int hl = idx & 1, rest = idx >> 1;
  int dt = rest % 13, rest2 = rest / 13;
  int kt = rest2 % KT, b = rest2 / KT;
  int t = kt * 32 + ((l >> 4) << 2) + (j & 3) + ((j >> 2) << 4);
  int d = dt * 16 + (l & 15);
  float v = xf[((size_t)b * KT * 32 + t) * XFS + d];
  float hi = (float)(f16)v;
  out[e] = hl ? (f16)((v - hi) * 2048.f) : (f16)v;
}

// ---------------------------------------------------------------- MFMA attention + fc1 + fc2

__global__ __launch_bounds__(256, 2) void attn_mfma(
    const f16* __restrict__ lfF, const f16* __restrict__ xFab, const f16* __restrict__ xFti,
    const f16* __restrict__ vFab, const f16* __restrict__ vFti,
    const float* __restrict__ fc1b, const float* __restrict__ fc2w,
    const float* __restrict__ fc2b, float* __restrict__ outp) {
  __shared__ float SB[2][32][65];
  __shared__ float CRS[2][2][16];
  __shared__ float LIS[2][2][16];

  int tid = threadIdx.x, lane = tid & 63, w = tid >> 6;
  int nh = w >> 1, hl = w & 1;
  int b = blockIdx.y, nt = blockIdx.x;
  int l15 = lane & 15, lg = lane >> 4;

  f32x4 acc[2][13];
#pragma unroll
  for (int ns = 0; ns < 2; ns++)
#pragma unroll
    for (int dt = 0; dt < 13; dt++) acc[ns][dt] = (f32x4){0.f, 0.f, 0.f, 0.f};
  float mrun[4] = {-INFINITY, -INFINITY, -INFINITY, -INFINITY};
  float lrun[4] = {0.f, 0.f, 0.f, 0.f};

  for (int c = 0; c < 7; c++) {
    const bool ti = (c == 6);
    const f16* xb = ti ? xFti + (size_t)b * (4 * 13 * 512)
                       : xFab + ((size_t)(b * 24 + c * 4)) * 13 * 512;
    f32x4 S[2][2];
#pragma unroll
    for (int ns = 0; ns < 2; ns++)
#pragma unroll
      for (int ts = 0; ts < 2; ts++) S[ns][ts] = (f32x4){0.f, 0.f, 0.f, 0.f};
#pragma unroll
    for (int kh = 0; kh < 2; kh++) {
      const int kt0 = kh ? 7 : 0;
      const int ktn = kh ? 6 : 7;
      f16x8 la[2][7];
#pragma unroll
      for (int ns = 0; ns < 2; ns++) {
        const f16* lp = lfF + (((size_t)(nt * 4 + nh * 2 + ns)) * 13 + kt0) * 512 + lane * 8;
#pragma unroll
        for (int k = 0; k < 7; k++)
          if (k < ktn) la[ns][k] = *(const f16x8*)(lp + (size_t)k * 512);
      }
#pragma unroll
      for (int ts = 0; ts < 2; ts++) {
        const f16* xp = xb + (((size_t)(hl * 2 + ts)) * 13 + kt0) * 512 + lane * 8;
        f16x8 xa[7];
#pragma unroll
        for (int k = 0; k < 7; k++)
          if (k < ktn) xa[k] = *(const f16x8*)(xp + (size_t)k * 512);
#pragma unroll
        for (int ns = 0; ns < 2; ns++)
#pragma unroll
          for (int k = 0; k < 7; k++)
            if (k < ktn)
              S[ns][ts] = __builtin_amdgcn_mfma_f32_16x16x32_f16(la[ns][k], xa[k], S[ns][ts], 0, 0, 0);
      }
    }
    __syncthreads();
#pragma unroll
    for (int ns = 0; ns < 2; ns++)
#pragma unroll
      for (int ts = 0; ts < 2; ts++)
#pragma unroll
        for (int r = 0; r < 4; r++)
          SB[nh][ns * 16 + lg * 4 + r][(hl * 2 + ts) * 16 + l15] = S[ns][ts][r];
    __syncthreads();
    {
      float vv[4][4];
#pragma unroll
      for (int r = 0; r < 4; r++)
#pragma unroll
        for (int ts = 0; ts < 4; ts++)
          vv[r][ts] = SB[nh][hl * 16 + lg * 4 + r][ts * 16 + l15];
#pragma unroll
      for (int r = 0; r < 4; r++) {
        float tm = fmaxf(fmaxf(vv[r][0], vv[r][1]), fmaxf(vv[r][2], vv[r][3]));
        tm = fmaxf(tm, __shfl_xor(tm, 1));
        tm = fmaxf(tm, __shfl_xor(tm, 2));
        tm = fmaxf(tm, __shfl_xor(tm, 4));
        tm = fmaxf(tm, __shfl_xor(tm, 8));
        if (!ti) {
          float mn = fmaxf(mrun[r], tm);
          float cr = expf(mrun[r] - mn);
          float s = 0.f;
#pragma unroll
          for (int ts = 0; ts < 4; ts++) { vv[r][ts] = expf(vv[r][ts] - mn); s += vv[r][ts]; }
          s += __shfl_xor(s, 1); s += __shfl_xor(s, 2);
          s += __shfl_xor(s, 4); s += __shfl_xor(s, 8);
          lrun[r] = lrun[r] * cr + s;
          mrun[r] = mn;
#pragma unroll
          for (int ts = 0; ts < 4; ts++)
            SB[nh][hl * 16 + lg * 4 + r][ts * 16 + l15] = vv[r][ts];
          if (l15 == 0) {
            CRS[nh][hl][lg * 4 + r] = cr;
            if (c == 5) LIS[nh][hl][lg * 4 + r] = 1.f / lrun[r];
          }
        } else {
          float s = 0.f;
#pragma unroll
          for (int ts = 0; ts < 4; ts++) { vv[r][ts] = expf(vv[r][ts] - tm); s += vv[r][ts]; }
          s += __shfl_xor(s, 1); s += __shfl_xor(s, 2);
          s += __shfl_xor(s, 4); s += __shfl_xor(s, 8);
          float inv = 1.f / s;
#pragma unroll
          for (int ts = 0; ts < 4; ts++)
            SB[nh][hl * 16 + lg * 4 + r][ts * 16 + l15] = vv[r][ts] * inv;
        }
      }
    }
    __syncthreads();
    if (!ti) {
#pragma unroll
      for (int ns = 0; ns < 2; ns++)
#pragma unroll
        for (int r = 0; r < 4; r++) {
          float cr = CRS[nh][ns][lg * 4 + r];
#pragma unroll
          for (int dt = 0; dt < 13; dt++) acc[ns][dt][r] *= cr;
        }
    } else {
#pragma unroll
      for (int ns = 0; ns < 2; ns++)
#pragma unroll
        for (int r = 0; r < 4; r++) {
          float li = LIS[nh][ns][lg * 4 + r];
#pragma unroll
          for (int dt = 0; dt < 13; dt++) acc[ns][dt][r] *= li;
        }
    }
    f16x8 pf[2][2];
#pragma unroll
    for (int ns = 0; ns < 2; ns++)
#pragma unroll
      for (int kt = 0; kt < 2; kt++)
#pragma unroll
        for (int j = 0; j < 8; j++) {
          int col = kt * 32 + (lg << 2) + (j & 3) + ((j >> 2) << 4);
          pf[ns][kt][j] = (f16)SB[nh][ns * 16 + l15][col];
        }
#pragma unroll
    for (int dt = 0; dt < 13; dt++)
#pragma unroll
      for (int kt = 0; kt < 2; kt++) {
        const f16* vp = (ti ? vFti + (((size_t)((b * 2 + kt) * 13 + dt)) * 2 + hl) * 512
                            : vFab + (((size_t)((b * 12 + c * 2 + kt) * 13 + dt)) * 2 + hl) * 512)
                        + lane * 8;
        f16x8 vf = *(const f16x8*)vp;
#pragma unroll
        for (int ns = 0; ns < 2; ns++)
          acc[ns][dt] = __builtin_amdgcn_mfma_f32_16x16x32_f16(pf[ns][kt], vf, acc[ns][dt], 0, 0, 0);
      }
  }

  float part[2][4] = {{0.f, 0.f, 0.f, 0.f}, {0.f, 0.f, 0.f, 0.f}};
#pragma unroll
  for (int p = 0; p < 4; p++) {
    const int dt0 = p * 4;
    const int dtn = (p == 3) ? 1 : 4;
    __syncthreads();
    if (hl) {
#pragma unroll
      for (int ns = 0; ns < 2; ns++)
#pragma unroll
        for (int q = 0; q < 4; q++)
          if (q < dtn)
#pragma unroll
            for (int r = 0; r < 4; r++)
              SB[nh][ns * 16 + lg * 4 + r][q * 16 + l15] = acc[ns][dt0 + q][r];
    }
    __syncthreads();
    if (!hl) {
#pragma unroll
      for (int ns = 0; ns < 2; ns++)
#pragma unroll
        for (int q = 0; q < 4; q++)
          if (q < dtn)
#pragma unroll
            for (int r = 0; r < 4; r++) {
              int d = (dt0 + q) * 16 + l15;
              float y = acc[ns][dt0 + q][r] +
                        SB[nh][ns * 16 + lg * 4 + r][q * 16 + l15] * (1.f / 2048.f);
              if (d < 200) {
                y += fc1b[d];
                y = y >= 0.f ? y : 0.2f * y;
                part[ns][r] = fmaf(y, fc2w[d], part[ns][r]);
              }
            }
    }
  }
  if (!hl) {
#pragma unroll
    for (int ns = 0; ns < 2; ns++)
#pragma unroll
      for (int r = 0; r < 4; r++) {
        float s = part[ns][r];
        s += __shfl_xor(s, 1); s += __shfl_xor(s, 2);
        s += __shfl_xor(s, 4); s += __shfl_xor(s, 8);
        part[ns][r] = s;
      }
    if (l15 == 0) {
      float f2b = fc2b[0];
#pragma unroll
      for (int ns = 0; ns < 2; ns++)
#pragma unroll
        for (int r = 0; r < 4; r++) {
          int label = nt * 64 + nh * 32 + ns * 16 + lg * 4 + r;
          if (label < NLAB) {
            float y = part[ns][r] + f2b;
            y = y >= 0.f ? y : 0.2f * y;
            outp[(size_t)b * NLAB + label] = y;
          }
        }
    }
  }
}

// ---------------------------------------------------------------- launch

extern "C" void kernel_launch(void* const* d_in, const int* in_sizes, int n_in,
                              void* d_out, int out_size, void* d_ws, size_t ws_size,
                              hipStream_t stream) {
  (void)in_sizes; (void)n_in; (void)out_size; (void)ws_size;
  const int* tok_ab = (const int*)d_in[0];
  const int* tok_ti = (const int*)d_in[1];
  const int* len_ab = (const int*)d_in[2];
  const int* len_ti = (const int*)d_in[3];
  const int* esrc = (const int*)d_in[4];
  const int* edst = (const int*)d_in[5];
  const float* gnf = (const float*)d_in[6];
  const float* emb = (const float*)d_in[7];
  const float* wih0f = (const float*)d_in[8],  *whh0f = (const float*)d_in[9];
  const float* bih0f = (const float*)d_in[10], *bhh0f = (const float*)d_in[11];
  const float* wih0b = (const float*)d_in[12], *whh0b = (const float*)d_in[13];
  const float* bih0b = (const float*)d_in[14], *bhh0b = (const float*)d_in[15];
  const float* wih1f = (const float*)d_in[16], *whh1f = (const float*)d_in[17];
  const float* bih1f = (const float*)d_in[18], *bhh1f = (const float*)d_in[19];
  const float* wih1b = (const float*)d_in[20], *whh1b = (const float*)d_in[21];
  const float* bih1b = (const float*)d_in[22], *bhh1b = (const float*)d_in[23];
  const float* gw1 = (const float*)d_in[24], *gb1 = (const float*)d_in[25];
  const float* gw2 = (const float*)d_in[26], *gb2 = (const float*)d_in[27];
  const float* fc1w = (const float*)d_in[28], *fc1b = (const float*)d_in[29];
  const float* fc2w = (const float*)d_in[30], *fc2b = (const float*)d_in[31];

  float* W = (float*)d_ws;
  float* agg  = W;                 // 5,600,000 f
  f16*   lfF  = (f16*)W;           // overlays agg after gather/gemm done
  float* hbuf = W + 5830656;
  float* lab  = W + 5830656;
  float* x0ab   = W + 11200000;    // 307,200 (dead after gx-l0 gemms)
  float* x0ti   = W + 11507200;    // 51,200
  int*   cnt    = (int*)(W + 11550000);
  float* whhF0f = W + 11558400;
  float* whhF0b = W + 11701760;
  float* whhF1f = W + 11845120;
  float* whhF1b = W + 11988480;
  float* gxfab  = W + 12131840;
  float* gxbab  = W + 13053440;
  float* gxfti  = W + 13975040;
  float* gxbti  = W + 14128640;
  float* out0ab = W + 14282240;
  float* out0ti = W + 14896640;
  float* out1ab = W + 14999040;
  float* out1ti = W + 15613440;
  float* xf1ab  = W + 15715840;
  float* xf1ti  = W + 16059904;
  f16* xFab = (f16*)(W + 12131840);
  f16* xFti = (f16*)(W + 12451328);
  f16* vFab = (f16*)(W + 12504576);
  f16* vFti = (f16*)(W + 12824064);

  dim3 gGxAb(10, 24), gGxTi(10, 4);
  int packN = (40 * 7 * 512 + 255) / 256;

  // ---- prep ----
  embed_gather<<<(1536 * 50 + 255) / 256, 256, 0, stream>>>(tok_ab, emb, x0ab, 1536);
  embed_gather<<<(256 * 50 + 255) / 256, 256, 0, stream>>>(tok_ti, emb, x0ti, 256);
  pack_whhF<<<packN, 256, 0, stream>>>(whh0f, (f16*)whhF0f);
  pack_whhF<<<packN, 256, 0, stream>>>(whh0b, (f16*)whhF0b);
  pack_whhF<<<packN, 256, 0, stream>>>(whh1f, (f16*)whhF1f);
  pack_whhF<<<packN, 256, 0, stream>>>(whh1b, (f16*)whhF1b);
  hipMemsetAsync(out0ab, 0, (size_t)1835008 * sizeof(float), stream);

  // ---- gx layer-0 ----
  gemm_nt<0, 1><<<gGxAb, 256, 0, stream>>>(x0ab, wih0f, bih0f, gxfab, 1536, 600, 200, 600);
  gemm_nt<0, 1><<<gGxAb, 256, 0, stream>>>(x0ab, wih0b, bih0b, gxbab, 1536, 600, 200, 600);
  gemm_nt<0, 1><<<gGxTi, 256, 0, stream>>>(x0ti, wih0f, bih0f, gxfti, 256, 600, 200, 600);
  gemm_nt<0, 1><<<gGxTi, 256, 0, stream>>>(x0ti, wih0b, bih0b, gxbti, 256, 600, 200, 600);
  hipMemsetAsync(agg, 0, 5600000 * sizeof(float), stream);
  hipMemsetAsync(cnt, 0, 2 * sizeof(int), stream);

  RecurArgs r0;
  r0.gx[0] = gxfab; r0.gx[1] = gxbab; r0.gx[2] = gxfti; r0.gx[3] = gxbti;
  r0.wF[0] = whhF0f; r0.wF[1] = whhF0b; r0.wF[2] = whhF0f; r0.wF[3] = whhF0b;
  r0.bh[0] = bhh0f; r0.bh[1] = bhh0b; r0.bh[2] = bhh0f; r0.bh[3] = bhh0b;
  r0.out[0] = out0ab; r0.out[1] = out0ab; r0.out[2] = out0ti; r0.out[3] = out0ti;
  r0.len[0] = len_ab; r0.len[1] = len_ab; r0.len[2] = len_ti; r0.len[3] = len_ti;
  r0.Tl[0] = 384; r0.Tl[1] = 384; r0.Tl[2] = 64; r0.Tl[3] = 64;
  r0.dir[0] = 0; r0.dir[1] = 1; r0.dir[2] = 0; r0.dir[3] = 1;
  // ---- dispatch A: GRU0 + gather1(gnf->agg) + gemm1(agg->hbuf, relu) ----
  gru_fused<<<68, 512, 0, stream>>>(r0, gnf, esrc, edst, agg,
                                    gw1, gb1, hbuf, 1, 0, gnf, lfF, cnt);

  hipMemsetAsync(agg, 0, 5600000 * sizeof(float), stream);
  hipMemsetAsync(cnt, 0, 2 * sizeof(int), stream);
  gemm_nt<0, 1><<<gGxAb, 256, 0, stream>>>(out0ab, wih1f, bih1f, gxfab, 1536, 600, 400, 600);
  gemm_nt<0, 1><<<gGxAb, 256, 0, stream>>>(out0ab, wih1b, bih1b, gxbab, 1536, 600, 400, 600);
  gemm_nt<0, 1><<<gGxTi, 256, 0, stream>>>(out0ti, wih1f, bih1f, gxfti, 256, 600, 400, 600);
  gemm_nt<0, 1><<<gGxTi, 256, 0, stream>>>(out0ti, wih1b, bih1b, gxbti, 256, 600, 400, 600);

  RecurArgs r1 = r0;
  r1.wF[0] = whhF1f; r1.wF[1] = whhF1b;
  r1.wF[2] = whhF1f; r1.wF[3] = whhF1b;
  r1.bh[0] = bhh1f; r1.bh[1] = bhh1b; r1.bh[2] = bhh1f; r1.bh[3] = bhh1b;
  r1.out[0] = out1ab; r1.out[1] = out1ab; r1.out[2] = out1ti; r1.out[3] = out1ti;
  // ---- dispatch B: GRU1 + gather2(hbuf->agg) + gemm2(agg->lab) + cvt_lf ----
  gru_fused<<<68, 512, 0, stream>>>(r1, hbuf, esrc, edst, agg,
                                    gw2, gb2, lab, 0, 1, gnf, lfF, cnt);

  // ---- xf1 = out1 @ fc1^T ----
  gemm_nt<0, 0><<<dim3(4, 24), 256, 0, stream>>>(out1ab, fc1w, nullptr, xf1ab, 1536, 200, 400, XFS);
  gemm_nt<0, 0><<<dim3(4, 4), 256, 0, stream>>>(out1ti, fc1w, nullptr, xf1ti, 256, 200, 400, XFS);

  // ---- x / V fragments ----
  cvt_x_frags<<<(4 * 24 * 13 * 512 + 255) / 256, 256, 0, stream>>>(out1ab, xFab, 24);
  cvt_x_frags<<<(4 * 4 * 13 * 512 + 255) / 256, 256, 0, stream>>>(out1ti, xFti, 4);
  cvt_v_frags<<<(4 * 12 * 13 * 2 * 512 + 255) / 256, 256, 0, stream>>>(xf1ab, vFab, 12);
  cvt_v_frags<<<(4 * 2 * 13 * 2 * 512 + 255) / 256, 256, 0, stream>>>(xf1ti, vFti, 2);

  // ---- fused MFMA attention ----
  attn_mfma<<<dim3(438, 4), 256, 0, stream>>>(
      lfF, xFab, xFti, vFab, vFti, fc1b, fc2w, fc2b, (float*)d_out);
}

// Round 16
// 5369.011 us; speedup vs baseline: 1.2799x; 1.2799x over previous
//
#include <hip/hip_runtime.h>
#include <math.h>

#define NLAB 28000
#define NEDGE 224000
#define XFS 224

typedef _Float16 f16;
typedef _Float16 f16x8 __attribute__((ext_vector_type(8)));
typedef float f32x4 __attribute__((ext_vector_type(4)));

// ---------------------------------------------------------------- utils

__device__ __forceinline__ void atomAddF(float* p, float v) {
  unsafeAtomicAdd(p, v);
}

struct RecurArgs {
  const float* gx[4];
  const float* wF[4];   // packed f16 frags: hi[40*7*512] then lo[40*7*512]
  const float* bh[4];
  float* out[4];
  const int* len[4];
  int Tl[4];
  int dir[4];
};

#define COMPB(V, B) ((B) == 0 ? (V).x : (B) == 1 ? (V).y : (B) == 2 ? (V).z : (V).w)

// ---------------------------------------------------------------- embed

__global__ void embed_gather(const int* __restrict__ tok, const float* __restrict__ emb,
                             float* __restrict__ x, int rows) {
  int idx = blockIdx.x * blockDim.x + threadIdx.x;
  if (idx >= rows * 50) return;
  int r = idx / 50, c = idx - r * 50;
  *(float4*)&x[(size_t)r * 200 + c * 4] =
      *(const float4*)&emb[(size_t)tok[r] * 200 + c * 4];
}

// ---------------------------------------------------------------- whh -> MFMA A-frag pack (f16 hi/lo)

__global__ void pack_whhF(const float* __restrict__ whh, f16* __restrict__ out) {
  int e = blockIdx.x * 256 + threadIdx.x;
  if (e >= 40 * 7 * 512) return;
  int frag = e >> 9, r = e & 511;
  int l = r >> 3, j = r & 7;
  int mt = frag / 7, kt = frag - mt * 7;
  int m = mt * 16 + (l & 15);
  int k = kt * 32 + ((l >> 4) << 2) + (j & 3) + ((j >> 2) << 4);
  float v = (m < 600 && k < 200) ? whh[(size_t)m * 200 + k] : 0.f;
  f16 hi = (f16)v;
  out[e] = hi;
  out[40 * 7 * 512 + e] = (f16)((v - (float)hi) * 2048.f);
}

// ---------------------------------------------------------------- generic C[M,N] = A[M,K] * W[N,K]^T (+bias)(+relu)

template <int RELU, int BIAS>
__global__ __launch_bounds__(256, 2) void gemm_nt(
    const float* __restrict__ A, const float* __restrict__ Wt,
    const float* __restrict__ bias, float* __restrict__ C,
    int M, int N, int K, int ldc) {
  __shared__ float As[16][68];
  __shared__ float Bs[16][68];
  int tx = threadIdx.x & 15, ty = threadIdx.x >> 4;
  int m0 = blockIdx.y * 64, n0 = blockIdx.x * 64;
  float c[4][4] = {};
  int row = threadIdx.x >> 2;
  int kk = (threadIdx.x & 3) * 4;
  for (int k0 = 0; k0 < K; k0 += 16) {
    int gk = k0 + kk;
    float a0 = 0, a1 = 0, a2 = 0, a3 = 0;
    float b0 = 0, b1 = 0, b2 = 0, b3 = 0;
    int gm = m0 + row;
    if (gm < M) {
      if (gk + 3 < K) {
        float4 v = *(const float4*)&A[(size_t)gm * K + gk];
        a0 = v.x; a1 = v.y; a2 = v.z; a3 = v.w;
      } else {
        if (gk + 0 < K) a0 = A[(size_t)gm * K + gk + 0];
        if (gk + 1 < K) a1 = A[(size_t)gm * K + gk + 1];
        if (gk + 2 < K) a2 = A[(size_t)gm * K + gk + 2];
        if (gk + 3 < K) a3 = A[(size_t)gm * K + gk + 3];
      }
    }
    int gn = n0 + row;
    if (gn < N) {
      if (gk + 3 < K) {
        float4 v = *(const float4*)&Wt[(size_t)gn * K + gk];
        b0 = v.x; b1 = v.y; b2 = v.z; b3 = v.w;
      } else {
        if (gk + 0 < K) b0 = Wt[(size_t)gn * K + gk + 0];
        if (gk + 1 < K) b1 = Wt[(size_t)gn * K + gk + 1];
        if (gk + 2 < K) b2 = Wt[(size_t)gn * K + gk + 2];
        if (gk + 3 < K) b3 = Wt[(size_t)gn * K + gk + 3];
      }
    }
    As[kk + 0][row] = a0; As[kk + 1][row] = a1; As[kk + 2][row] = a2; As[kk + 3][row] = a3;
    Bs[kk + 0][row] = b0; Bs[kk + 1][row] = b1; Bs[kk + 2][row] = b2; Bs[kk + 3][row] = b3;
    __syncthreads();
#pragma unroll
    for (int k = 0; k < 16; k++) {
      float4 a4 = *(const float4*)&As[k][ty * 4];
      float4 b4 = *(const float4*)&Bs[k][tx * 4];
      c[0][0] = fmaf(a4.x, b4.x, c[0][0]); c[0][1] = fmaf(a4.x, b4.y, c[0][1]);
      c[0][2] = fmaf(a4.x, b4.z, c[0][2]); c[0][3] = fmaf(a4.x, b4.w, c[0][3]);
      c[1][0] = fmaf(a4.y, b4.x, c[1][0]); c[1][1] = fmaf(a4.y, b4.y, c[1][1]);
      c[1][2] = fmaf(a4.y, b4.z, c[1][2]); c[1][3] = fmaf(a4.y, b4.w, c[1][3]);
      c[2][0] = fmaf(a4.z, b4.x, c[2][0]); c[2][1] = fmaf(a4.z, b4.y, c[2][1]);
      c[2][2] = fmaf(a4.z, b4.z, c[2][2]); c[2][3] = fmaf(a4.z, b4.w, c[2][3]);
      c[3][0] = fmaf(a4.w, b4.x, c[3][0]); c[3][1] = fmaf(a4.w, b4.y, c[3][1]);
      c[3][2] = fmaf(a4.w, b4.z, c[3][2]); c[3][3] = fmaf(a4.w, b4.w, c[3][3]);
    }
    __syncthreads();
  }
#pragma unroll
  for (int i = 0; i < 4; i++) {
    int gm = m0 + ty * 4 + i;
    if (gm >= M) continue;
#pragma unroll
    for (int j = 0; j < 4; j++) {
      int gn = n0 + tx * 4 + j;
      if (gn >= N) continue;
      float v = c[i][j];
      if (BIAS) v += bias[gn];
      if (RELU) v = fmaxf(v, 0.f);
      C[(size_t)gm * ldc + gn] = v;
    }
  }
}

// ---------------------------------------------------------------- GRU + GCN fused dispatch
// Blocks 0-3: GRU chain; 16 hi M-tiles LDS-resident, h/bhs in LDS (R13 best).
// Blocks 4..131: edge scatter-add, arrive barrier, inline GCN linear;
// dispatch B adds cvt_lf after a second barrier.

__global__ __launch_bounds__(512, 1) void gru_fused(RecurArgs a,
    const float* __restrict__ gfeat, const int* __restrict__ esrc,
    const int* __restrict__ edst, float* __restrict__ gagg,
    const float* __restrict__ gw, const float* __restrict__ gb,
    float* __restrict__ gout, int relu, int doCvt,
    const float* __restrict__ gnfp, f16* __restrict__ lfFp, int* __restrict__ cnt) {
  __shared__ __align__(16) f16 wlds[16][7][512];   // 112 KB hi tiles (gather blocks: arow alias)
  __shared__ __align__(16) f16 hfrag[2][7][512];   // [hi|lo][kt][frag]
  __shared__ float h[200][4];
  __shared__ float gh[600][4];
  __shared__ float bhs[600];
  __shared__ int lens[4];

  if (blockIdx.x >= 4) {
    int tid = threadIdx.x;
    int lane = tid & 63;
    int nb = gridDim.x - 4;
    // ---- GCN edge gather ----
    if (lane < 50) {
      int wav = (blockIdx.x - 4) * 8 + (tid >> 6);
      for (int e = wav; e < NEDGE; e += nb * 8) {
        int s = esrc[e], d = edst[e];
        float4 v = *(const float4*)&gfeat[(size_t)s * 200 + lane * 4];
        float* p = &gagg[(size_t)d * 200 + lane * 4];
        atomAddF(p + 0, v.x); atomAddF(p + 1, v.y);
        atomAddF(p + 2, v.z); atomAddF(p + 3, v.w);
      }
    }
    // ---- barrier 0: all gather atomics done ----
    __syncthreads();
    if (tid == 0) {
      __threadfence();
      __hip_atomic_fetch_add(&cnt[0], 1, __ATOMIC_ACQ_REL, __HIP_MEMORY_SCOPE_AGENT);
      while (__hip_atomic_load(&cnt[0], __ATOMIC_ACQUIRE, __HIP_MEMORY_SCOPE_AGENT) < nb) {}
    }
    __syncthreads();
    // ---- GCN linear ----
    float* arow = (float*)wlds;
    for (int m = blockIdx.x - 4; m < NLAB; m += nb) {
      __syncthreads();
      for (int k = tid; k < 200; k += 512) arow[k] = gagg[(size_t)m * 200 + k];
      __syncthreads();
      if (tid < 200) {
        float acc = gb[tid];
        const float* wr = gw + (size_t)tid * 200;
#pragma unroll 4
        for (int k = 0; k < 200; k++) acc = fmaf(arow[k], wr[k], acc);
        if (relu) acc = fmaxf(acc, 0.f);
        gout[(size_t)m * 200 + tid] = acc;
      }
    }
    if (doCvt) {
      __syncthreads();
      if (tid == 0) {
        __threadfence();
        __hip_atomic_fetch_add(&cnt[1], 1, __ATOMIC_ACQ_REL, __HIP_MEMORY_SCOPE_AGENT);
        while (__hip_atomic_load(&cnt[1], __ATOMIC_ACQUIRE, __HIP_MEMORY_SCOPE_AGENT) < nb) {}
      }
      __syncthreads();
      for (int e = (blockIdx.x - 4) * 512 + tid; e < 1752 * 13 * 512; e += nb * 512) {
        int frag = e >> 9, r = e & 511;
        int l = r >> 3, j = r & 7;
        int nsub = frag / 13, kt = frag - nsub * 13;
        int label = nsub * 16 + (l & 15);
        int k = kt * 32 + ((l >> 4) << 2) + (j & 3) + ((j >> 2) << 4);
        float v = 0.f;
        if (label < NLAB && k < 400)
          v = (k < 200) ? gout[(size_t)label * 200 + k] : gnfp[(size_t)label * 200 + k - 200];
        lfFp[e] = (f16)v;
      }
    }
    return;
  }

  int blk = blockIdx.x;
  const float* __restrict__ gx = a.gx[blk];
  const f16* __restrict__ whiP = (const f16*)a.wF[blk];
  const float* __restrict__ bh = a.bh[blk];
  float* __restrict__ outp = a.out[blk];
  const int* lenp = a.len[blk];
  int TT = a.Tl[blk];
  int bwd = a.dir[blk];
  int dirOff = bwd ? 200 : 0;

  int tid = threadIdx.x, lane = tid & 63, w = tid >> 6;
  int l15 = lane & 15, lg = lane >> 4;

  for (int i = tid; i < 800; i += 512) ((float*)h)[i] = 0.f;
  for (int i = tid; i < 600; i += 512) bhs[i] = bh[i];
  for (int i = tid; i < 2 * 7 * 512; i += 512) ((f16*)hfrag)[i] = (f16)0.f;
  if (tid < 4) lens[tid] = lenp[tid];

  // one-time fill of LDS-resident hi tiles (wave w: M-tiles 5w, 5w+1)
#pragma unroll
  for (int i = 0; i < 2; i++)
#pragma unroll
    for (int kt = 0; kt < 7; kt++)
      *(f16x8*)&wlds[w * 2 + i][kt][lane * 8] =
          *(const f16x8*)(whiP + ((size_t)((w * 5 + i) * 7 + kt)) * 512 + lane * 8);
  __syncthreads();
  int maxlen = max(max(lens[0], lens[1]), max(lens[2], lens[3]));

  for (int s = 0; s < maxlen; s++) {
    // ---- gx prefetch: retire under phase A's weight stream
    float pgx[3][4];
    if (tid < 200) {
#pragma unroll
      for (int b = 0; b < 4; b++) {
        int Lb = lens[b];
        if (s < Lb) {
          int ta = bwd ? (Lb - 1 - s) : s;
          const float* gxr = gx + (size_t)(b * TT + ta) * 600;
          pgx[0][b] = gxr[tid];
          pgx[1][b] = gxr[200 + tid];
          pgx[2][b] = gxr[400 + tid];
        }
      }
    }
    // ---- phase A: MFMA matvec (hi: 2 tiles LDS + 3 streamed; lo: 5 streamed)
    f32x4 acc1[5], acc2[5];
#pragma unroll
    for (int i = 0; i < 5; i++) {
      acc1[i] = (f32x4){0.f, 0.f, 0.f, 0.f};
      acc2[i] = (f32x4){0.f, 0.f, 0.f, 0.f};
    }
#pragma unroll
    for (int kt = 0; kt < 7; kt++) {
      f16x8 hhi = *(const f16x8*)&hfrag[0][kt][lane * 8];
      f16x8 hlo = *(const f16x8*)&hfrag[1][kt][lane * 8];
#pragma unroll
      for (int i = 0; i < 5; i++) {
        const f16* base = whiP + ((size_t)((w * 5 + i) * 7 + kt)) * 512 + lane * 8;
        f16x8 whi = (i < 2) ? *(const f16x8*)&wlds[w * 2 + i][kt][lane * 8]
                            : *(const f16x8*)base;
        f16x8 wlo = *(const f16x8*)(base + (size_t)40 * 7 * 512);
        acc1[i] = __builtin_amdgcn_mfma_f32_16x16x32_f16(whi, hhi, acc1[i], 0, 0, 0);
        acc2[i] = __builtin_amdgcn_mfma_f32_16x16x32_f16(wlo, hhi, acc2[i], 0, 0, 0);
        acc2[i] = __builtin_amdgcn_mfma_f32_16x16x32_f16(whi, hlo, acc2[i], 0, 0, 0);
      }
    }
    if (l15 < 4) {
#pragma unroll
      for (int i = 0; i < 5; i++) {
        int mbase = (w * 5 + i) * 16 + lg * 4;
#pragma unroll
        for (int r = 0; r < 4; r++) {
          int m = mbase + r;
          if (m < 600) gh[m][l15] = acc1[i][r] + acc2[i][r] * (1.f / 2048.f);
        }
      }
    }
    __syncthreads();
    // ---- phase B: gates + h update + output + h-frag write
    if (tid < 200) {
      int u = tid;
      float4 hold = *(const float4*)&h[u][0];
      float4 hnew = hold;
      float br = bhs[u], bz = bhs[200 + u], bn = bhs[400 + u];
#pragma unroll
      for (int b = 0; b < 4; b++) {
        int Lb = lens[b];
        if (s < Lb) {
          int ta = bwd ? (Lb - 1 - s) : s;
          float r = 1.f / (1.f + expf(-(pgx[0][b] + gh[u][b] + br)));
          float z = 1.f / (1.f + expf(-(pgx[1][b] + gh[200 + u][b] + bz)));
          float n = tanhf(pgx[2][b] + r * (gh[400 + u][b] + bn));
          float hn = (1.f - z) * n + z * COMPB(hold, b);
          if (b == 0) hnew.x = hn; else if (b == 1) hnew.y = hn;
          else if (b == 2) hnew.z = hn; else hnew.w = hn;
          outp[(size_t)(b * TT + ta) * 400 + dirOff + u] = hn;
        }
      }
      *(float4*)&h[u][0] = hnew;
      int kt = u >> 5;
      int lbase = ((u >> 2) & 3) << 4;
      int j = (u & 3) | (((u >> 4) & 1) << 2);
#pragma unroll
      for (int b = 0; b < 4; b++) {
        float hv = COMPB(hnew, b);
        f16 hi = (f16)hv;
        f16 lo = (f16)((hv - (float)hi) * 2048.f);
        hfrag[0][kt][(lbase + b) * 8 + j] = hi;
        hfrag[1][kt][(lbase + b) * 8 + j] = lo;
      }
    }
    __syncthreads();
  }
}

// ---------------------------------------------------------------- f16 fragment prep kernels

__global__ void cvt_x_frags(const float* __restrict__ x, f16* __restrict__ out, int TT) {
  int e = blockIdx.x * 256 + threadIdx.x;
  if (e >= 4 * TT * 13 * 512) return;
  int frag = e >> 9, r = e & 511;
  int l = r >> 3, j = r & 7;
  int kt = frag % 13, bt = frag / 13;
  int tt = bt % TT, b = bt / TT;
  int t = tt * 16 + (l & 15);
  int k = kt * 32 + ((l >> 4) << 2) + (j & 3) + ((j >> 2) << 4);
  float v = (k < 400) ? x[((size_t)b * TT * 16 + t) * 400 + k] : 0.f;
  out[e] = (f16)v;
}

__global__ void cvt_v_frags(const float* __restrict__ xf, f16* __restrict__ out, int KT) {
  int e = blockIdx.x * 256 + threadIdx.x;
  if (e >= 4 * KT * 13 * 2 * 512) return;
  int idx = e >> 9, r = e & 511;
  int l = r >> 3, j = r & 7;
  int hl = idx & 1, rest = idx >> 1;
  int dt = rest % 13, rest2 = rest / 13;
  int kt = rest2 % KT, b = rest2 / KT;
  int t = kt * 32 + ((l >> 4) << 2) + (j & 3) + ((j >> 2) << 4);
  int d = dt * 16 + (l & 15);
  float v = xf[((size_t)b * KT * 32 + t) * XFS + d];
  float hi = (float)(f16)v;
  out[e] = hl ? (f16)((v - hi) * 2048.f) : (f16)v;
}

// ---------------------------------------------------------------- MFMA attention + fc1 + fc2

__global__ __launch_bounds__(256, 2) void attn_mfma(
    const f16* __restrict__ lfF, const f16* __restrict__ xFab, const f16* __restrict__ xFti,
    const f16* __restrict__ vFab, const f16* __restrict__ vFti,
    const float* __restrict__ fc1b, const float* __restrict__ fc2w,
    const float* __restrict__ fc2b, float* __restrict__ outp) {
  __shared__ float SB[2][32][65];
  __shared__ float CRS[2][2][16];
  __shared__ float LIS[2][2][16];

  int tid = threadIdx.x, lane = tid & 63, w = tid >> 6;
  int nh = w >> 1, hl = w & 1;
  int b = blockIdx.y, nt = blockIdx.x;
  int l15 = lane & 15, lg = lane >> 4;

  f32x4 acc[2][13];
#pragma unroll
  for (int ns = 0; ns < 2; ns++)
#pragma unroll
    for (int dt = 0; dt < 13; dt++) acc[ns][dt] = (f32x4){0.f, 0.f, 0.f, 0.f};
  float mrun[4] = {-INFINITY, -INFINITY, -INFINITY, -INFINITY};
  float lrun[4] = {0.f, 0.f, 0.f, 0.f};

  for (int c = 0; c < 7; c++) {
    const bool ti = (c == 6);
    const f16* xb = ti ? xFti + (size_t)b * (4 * 13 * 512)
                       : xFab + ((size_t)(b * 24 + c * 4)) * 13 * 512;
    f32x4 S[2][2];
#pragma unroll
    for (int ns = 0; ns < 2; ns++)
#pragma unroll
      for (int ts = 0; ts < 2; ts++) S[ns][ts] = (f32x4){0.f, 0.f, 0.f, 0.f};
#pragma unroll
    for (int kh = 0; kh < 2; kh++) {
      const int kt0 = kh ? 7 : 0;
      const int ktn = kh ? 6 : 7;
      f16x8 la[2][7];
#pragma unroll
      for (int ns = 0; ns < 2; ns++) {
        const f16* lp = lfF + (((size_t)(nt * 4 + nh * 2 + ns)) * 13 + kt0) * 512 + lane * 8;
#pragma unroll
        for (int k = 0; k < 7; k++)
          if (k < ktn) la[ns][k] = *(const f16x8*)(lp + (size_t)k * 512);
      }
#pragma unroll
      for (int ts = 0; ts < 2; ts++) {
        const f16* xp = xb + (((size_t)(hl * 2 + ts)) * 13 + kt0) * 512 + lane * 8;
        f16x8 xa[7];
#pragma unroll
        for (int k = 0; k < 7; k++)
          if (k < ktn) xa[k] = *(const f16x8*)(xp + (size_t)k * 512);
#pragma unroll
        for (int ns = 0; ns < 2; ns++)
#pragma unroll
          for (int k = 0; k < 7; k++)
            if (k < ktn)
              S[ns][ts] = __builtin_amdgcn_mfma_f32_16x16x32_f16(la[ns][k], xa[k], S[ns][ts], 0, 0, 0);
      }
    }
    __syncthreads();
#pragma unroll
    for (int ns = 0; ns < 2; ns++)
#pragma unroll
      for (int ts = 0; ts < 2; ts++)
#pragma unroll
        for (int r = 0; r < 4; r++)
          SB[nh][ns * 16 + lg * 4 + r][(hl * 2 + ts) * 16 + l15] = S[ns][ts][r];
    __syncthreads();
    {
      float vv[4][4];
#pragma unroll
      for (int r = 0; r < 4; r++)
#pragma unroll
        for (int ts = 0; ts < 4; ts++)
          vv[r][ts] = SB[nh][hl * 16 + lg * 4 + r][ts * 16 + l15];
#pragma unroll
      for (int r = 0; r < 4; r++) {
        float tm = fmaxf(fmaxf(vv[r][0], vv[r][1]), fmaxf(vv[r][2], vv[r][3]));
        tm = fmaxf(tm, __shfl_xor(tm, 1));
        tm = fmaxf(tm, __shfl_xor(tm, 2));
        tm = fmaxf(tm, __shfl_xor(tm, 4));
        tm = fmaxf(tm, __shfl_xor(tm, 8));
        if (!ti) {
          float mn = fmaxf(mrun[r], tm);
          float cr = expf(mrun[r] - mn);
          float s = 0.f;
#pragma unroll
          for (int ts = 0; ts < 4; ts++) { vv[r][ts] = expf(vv[r][ts] - mn); s += vv[r][ts]; }
          s += __shfl_xor(s, 1); s += __shfl_xor(s, 2);
          s += __shfl_xor(s, 4); s += __shfl_xor(s, 8);
          lrun[r] = lrun[r] * cr + s;
          mrun[r] = mn;
#pragma unroll
          for (int ts = 0; ts < 4; ts++)
            SB[nh][hl * 16 + lg * 4 + r][ts * 16 + l15] = vv[r][ts];
          if (l15 == 0) {
            CRS[nh][hl][lg * 4 + r] = cr;
            if (c == 5) LIS[nh][hl][lg * 4 + r] = 1.f / lrun[r];
          }
        } else {
          float s = 0.f;
#pragma unroll
          for (int ts = 0; ts < 4; ts++) { vv[r][ts] = expf(vv[r][ts] - tm); s += vv[r][ts]; }
          s += __shfl_xor(s, 1); s += __shfl_xor(s, 2);
          s += __shfl_xor(s, 4); s += __shfl_xor(s, 8);
          float inv = 1.f / s;
#pragma unroll
          for (int ts = 0; ts < 4; ts++)
            SB[nh][hl * 16 + lg * 4 + r][ts * 16 + l15] = vv[r][ts] * inv;
        }
      }
    }
    __syncthreads();
    if (!ti) {
#pragma unroll
      for (int ns = 0; ns < 2; ns++)
#pragma unroll
        for (int r = 0; r < 4; r++) {
          float cr = CRS[nh][ns][lg * 4 + r];
#pragma unroll
          for (int dt = 0; dt < 13; dt++) acc[ns][dt][r] *= cr;
        }
    } else {
#pragma unroll
      for (int ns = 0; ns < 2; ns++)
#pragma unroll
        for (int r = 0; r < 4; r++) {
          float li = LIS[nh][ns][lg * 4 + r];
#pragma unroll
          for (int dt = 0; dt < 13; dt++) acc[ns][dt][r] *= li;
        }
    }
    f16x8 pf[2][2];
#pragma unroll
    for (int ns = 0; ns < 2; ns++)
#pragma unroll
      for (int kt = 0; kt < 2; kt++)
#pragma unroll
        for (int j = 0; j < 8; j++) {
          int col = kt * 32 + (lg << 2) + (j & 3) + ((j >> 2) << 4);
          pf[ns][kt][j] = (f16)SB[nh][ns * 16 + l15][col];
        }
#pragma unroll
    for (int dt = 0; dt < 13; dt++)
#pragma unroll
      for (int kt = 0; kt < 2; kt++) {
        const f16* vp = (ti ? vFti + (((size_t)((b * 2 + kt) * 13 + dt)) * 2 + hl) * 512
                            : vFab + (((size_t)((b * 12 + c * 2 + kt) * 13 + dt)) * 2 + hl) * 512)
                        + lane * 8;
        f16x8 vf = *(const f16x8*)vp;
#pragma unroll
        for (int ns = 0; ns < 2; ns++)
          acc[ns][dt] = __builtin_amdgcn_mfma_f32_16x16x32_f16(pf[ns][kt], vf, acc[ns][dt], 0, 0, 0);
      }
  }

  float part[2][4] = {{0.f, 0.f, 0.f, 0.f}, {0.f, 0.f, 0.f, 0.f}};
#pragma unroll
  for (int p = 0; p < 4; p++) {
    const int dt0 = p * 4;
    const int dtn = (p == 3) ? 1 : 4;
    __syncthreads();
    if (hl) {
#pragma unroll
      for (int ns = 0; ns < 2; ns++)
#pragma unroll
        for (int q = 0; q < 4; q++)
          if (q < dtn)
#pragma unroll
            for (int r = 0; r < 4; r++)
              SB[nh][ns * 16 + lg * 4 + r][q * 16 + l15] = acc[ns][dt0 + q][r];
    }
    __syncthreads();
    if (!hl) {
#pragma unroll
      for (int ns = 0; ns < 2; ns++)
#pragma unroll
        for (int q = 0; q < 4; q++)
          if (q < dtn)
#pragma unroll
            for (int r = 0; r < 4; r++) {
              int d = (dt0 + q) * 16 + l15;
              float y = acc[ns][dt0 + q][r] +
                        SB[nh][ns * 16 + lg * 4 + r][q * 16 + l15] * (1.f / 2048.f);
              if (d < 200) {
                y += fc1b[d];
                y = y >= 0.f ? y : 0.2f * y;
                part[ns][r] = fmaf(y, fc2w[d], part[ns][r]);
              }
            }
    }
  }
  if (!hl) {
#pragma unroll
    for (int ns = 0; ns < 2; ns++)
#pragma unroll
      for (int r = 0; r < 4; r++) {
        float s = part[ns][r];
        s += __shfl_xor(s, 1); s += __shfl_xor(s, 2);
        s += __shfl_xor(s, 4); s += __shfl_xor(s, 8);
        part[ns][r] = s;
      }
    if (l15 == 0) {
      float f2b = fc2b[0];
#pragma unroll
      for (int ns = 0; ns < 2; ns++)
#pragma unroll
        for (int r = 0; r < 4; r++) {
          int label = nt * 64 + nh * 32 + ns * 16 + lg * 4 + r;
          if (label < NLAB) {
            float y = part[ns][r] + f2b;
            y = y >= 0.f ? y : 0.2f * y;
            outp[(size_t)b * NLAB + label] = y;
          }
        }
    }
  }
}

// ---------------------------------------------------------------- launch

extern "C" void kernel_launch(void* const* d_in, const int* in_sizes, int n_in,
                              void* d_out, int out_size, void* d_ws, size_t ws_size,
                              hipStream_t stream) {
  (void)in_sizes; (void)n_in; (void)out_size; (void)ws_size;
  const int* tok_ab = (const int*)d_in[0];
  const int* tok_ti = (const int*)d_in[1];
  const int* len_ab = (const int*)d_in[2];
  const int* len_ti = (const int*)d_in[3];
  const int* esrc = (const int*)d_in[4];
  const int* edst = (const int*)d_in[5];
  const float* gnf = (const float*)d_in[6];
  const float* emb = (const float*)d_in[7];
  const float* wih0f = (const float*)d_in[8],  *whh0f = (const float*)d_in[9];
  const float* bih0f = (const float*)d_in[10], *bhh0f = (const float*)d_in[11];
  const float* wih0b = (const float*)d_in[12], *whh0b = (const float*)d_in[13];
  const float* bih0b = (const float*)d_in[14], *bhh0b = (const float*)d_in[15];
  const float* wih1f = (const float*)d_in[16], *whh1f = (const float*)d_in[17];
  const float* bih1f = (const float*)d_in[18], *bhh1f = (const float*)d_in[19];
  const float* wih1b = (const float*)d_in[20], *whh1b = (const float*)d_in[21];
  const float* bih1b = (const float*)d_in[22], *bhh1b = (const float*)d_in[23];
  const float* gw1 = (const float*)d_in[24], *gb1 = (const float*)d_in[25];
  const float* gw2 = (const float*)d_in[26], *gb2 = (const float*)d_in[27];
  const float* fc1w = (const float*)d_in[28], *fc1b = (const float*)d_in[29];
  const float* fc2w = (const float*)d_in[30], *fc2b = (const float*)d_in[31];

  float* W = (float*)d_ws;
  float* agg  = W;                 // 5,600,000 f
  f16*   lfF  = (f16*)W;           // overlays agg after gather/gemm done
  float* hbuf = W + 5830656;
  float* lab  = W + 5830656;
  float* x0ab   = W + 11200000;    // 307,200 (dead after gx-l0 gemms)
  float* x0ti   = W + 11507200;    // 51,200
  int*   cnt    = (int*)(W + 11550000);
  float* whhF0f = W + 11558400;
  float* whhF0b = W + 11701760;
  float* whhF1f = W + 11845120;
  float* whhF1b = W + 11988480;
  float* gxfab  = W + 12131840;
  float* gxbab  = W + 13053440;
  float* gxfti  = W + 13975040;
  float* gxbti  = W + 14128640;
  float* out0ab = W + 14282240;
  float* out0ti = W + 14896640;
  float* out1ab = W + 14999040;
  float* out1ti = W + 15613440;
  float* xf1ab  = W + 15715840;
  float* xf1ti  = W + 16059904;
  f16* xFab = (f16*)(W + 12131840);
  f16* xFti = (f16*)(W + 12451328);
  f16* vFab = (f16*)(W + 12504576);
  f16* vFti = (f16*)(W + 12824064);

  dim3 gGxAb(10, 24), gGxTi(10, 4);
  int packN = (40 * 7 * 512 + 255) / 256;

  // ---- prep ----
  embed_gather<<<(1536 * 50 + 255) / 256, 256, 0, stream>>>(tok_ab, emb, x0ab, 1536);
  embed_gather<<<(256 * 50 + 255) / 256, 256, 0, stream>>>(tok_ti, emb, x0ti, 256);
  pack_whhF<<<packN, 256, 0, stream>>>(whh0f, (f16*)whhF0f);
  pack_whhF<<<packN, 256, 0, stream>>>(whh0b, (f16*)whhF0b);
  pack_whhF<<<packN, 256, 0, stream>>>(whh1f, (f16*)whhF1f);
  pack_whhF<<<packN, 256, 0, stream>>>(whh1b, (f16*)whhF1b);
  hipMemsetAsync(out0ab, 0, (size_t)1835008 * sizeof(float), stream);

  // ---- gx layer-0 ----
  gemm_nt<0, 1><<<gGxAb, 256, 0, stream>>>(x0ab, wih0f, bih0f, gxfab, 1536, 600, 200, 600);
  gemm_nt<0, 1><<<gGxAb, 256, 0, stream>>>(x0ab, wih0b, bih0b, gxbab, 1536, 600, 200, 600);
  gemm_nt<0, 1><<<gGxTi, 256, 0, stream>>>(x0ti, wih0f, bih0f, gxfti, 256, 600, 200, 600);
  gemm_nt<0, 1><<<gGxTi, 256, 0, stream>>>(x0ti, wih0b, bih0b, gxbti, 256, 600, 200, 600);
  hipMemsetAsync(agg, 0, 5600000 * sizeof(float), stream);
  hipMemsetAsync(cnt, 0, 2 * sizeof(int), stream);

  RecurArgs r0;
  r0.gx[0] = gxfab; r0.gx[1] = gxbab; r0.gx[2] = gxfti; r0.gx[3] = gxbti;
  r0.wF[0] = whhF0f; r0.wF[1] = whhF0b; r0.wF[2] = whhF0f; r0.wF[3] = whhF0b;
  r0.bh[0] = bhh0f; r0.bh[1] = bhh0b; r0.bh[2] = bhh0f; r0.bh[3] = bhh0b;
  r0.out[0] = out0ab; r0.out[1] = out0ab; r0.out[2] = out0ti; r0.out[3] = out0ti;
  r0.len[0] = len_ab; r0.len[1] = len_ab; r0.len[2] = len_ti; r0.len[3] = len_ti;
  r0.Tl[0] = 384; r0.Tl[1] = 384; r0.Tl[2] = 64; r0.Tl[3] = 64;
  r0.dir[0] = 0; r0.dir[1] = 1; r0.dir[2] = 0; r0.dir[3] = 1;
  // ---- dispatch A: GRU0 + gather1(gnf->agg) + gemm1(agg->hbuf, relu) ----
  gru_fused<<<132, 512, 0, stream>>>(r0, gnf, esrc, edst, agg,
                                     gw1, gb1, hbuf, 1, 0, gnf, lfF, cnt);

  hipMemsetAsync(agg, 0, 5600000 * sizeof(float), stream);
  hipMemsetAsync(cnt, 0, 2 * sizeof(int), stream);
  gemm_nt<0, 1><<<gGxAb, 256, 0, stream>>>(out0ab, wih1f, bih1f, gxfab, 1536, 600, 400, 600);
  gemm_nt<0, 1><<<gGxAb, 256, 0, stream>>>(out0ab, wih1b, bih1b, gxbab, 1536, 600, 400, 600);
  gemm_nt<0, 1><<<gGxTi, 256, 0, stream>>>(out0ti, wih1f, bih1f, gxfti, 256, 600, 400, 600);
  gemm_nt<0, 1><<<gGxTi, 256, 0, stream>>>(out0ti, wih1b, bih1b, gxbti, 256, 600, 400, 600);

  RecurArgs r1 = r0;
  r1.wF[0] = whhF1f; r1.wF[1] = whhF1b;
  r1.wF[2] = whhF1f; r1.wF[3] = whhF1b;
  r1.bh[0] = bhh1f; r1.bh[1] = bhh1b; r1.bh[2] = bhh1f; r1.bh[3] = bhh1b;
  r1.out[0] = out1ab; r1.out[1] = out1ab; r1.out[2] = out1ti; r1.out[3] = out1ti;
  // ---- dispatch B: GRU1 + gather2(hbuf->agg) + gemm2(agg->lab) + cvt_lf ----
  gru_fused<<<132, 512, 0, stream>>>(r1, hbuf, esrc, edst, agg,
                                     gw2, gb2, lab, 0, 1, gnf, lfF, cnt);

  // ---- xf1 = out1 @ fc1^T ----
  gemm_nt<0, 0><<<dim3(4, 24), 256, 0, stream>>>(out1ab, fc1w, nullptr, xf1ab, 1536, 200, 400, XFS);
  gemm_nt<0, 0><<<dim3(4, 4), 256, 0, stream>>>(out1ti, fc1w, nullptr, xf1ti, 256, 200, 400, XFS);

  // ---- x / V fragments ----
  cvt_x_frags<<<(4 * 24 * 13 * 512 + 255) / 256, 256, 0, stream>>>(out1ab, xFab, 24);
  cvt_x_frags<<<(4 * 4 * 13 * 512 + 255) / 256, 256, 0, stream>>>(out1ti, xFti, 4);
  cvt_v_frags<<<(4 * 12 * 13 * 2 * 512 + 255) / 256, 256, 0, stream>>>(xf1ab, vFab, 12);
  cvt_v_frags<<<(4 * 2 * 13 * 2 * 512 + 255) / 256, 256, 0, stream>>>(xf1ti, vFti, 2);

  // ---- fused MFMA attention ----
  attn_mfma<<<dim3(438, 4), 256, 0, stream>>>(
      lfF, xFab, xFti, vFab, vFti, fc1b, fc2w, fc2b, (float*)d_out);
}